// Round 31
// baseline (430.998 us; speedup 1.0000x reference)
//
#include <hip/hip_runtime.h>
#include <math.h>

// ---------------- problem constants ----------------
constexpr int NRES = 384;          // N
constexpr int NSEQ = 256;          // S
constexpr int DM   = 64;           // MSA_S
constexpr int DZ   = 128;          // Z_D
constexpr int NH   = 8;            // H
constexpr int DH   = 32;           // C_H
constexpr int HC   = NH * DH;      // 256
constexpr int DOP  = 32;           // C_OPM
constexpr int FF   = 4 * DM;       // 256

constexpr int NPAIR = NRES * NRES;         // 147456
constexpr int NROWS = NSEQ * NRES;         // 98304
constexpr int ZTOT  = NPAIR * DZ;          // 18874368
constexpr int SD    = NSEQ * DH;           // 8192

typedef unsigned short ushort_t;
typedef unsigned char uchar_t;
typedef long long i64;
typedef __attribute__((ext_vector_type(8))) short short8;
typedef __attribute__((ext_vector_type(4))) float f32x4;
typedef __attribute__((ext_vector_type(4))) int int4_t;

__device__ __forceinline__ float wred_sum(float v) {
    #pragma unroll
    for (int off = 32; off; off >>= 1) v += __shfl_xor(v, off, 64);
    return v;
}
__device__ __forceinline__ float sigm(float x) { return 1.0f / (1.0f + expf(-x)); }
__device__ __forceinline__ ushort_t cvt_bf(float f) {
    unsigned u = __float_as_uint(f);
    unsigned r = (u + 0x7FFFu + ((u >> 16) & 1u)) >> 16;
    return (ushort_t)r;
}
__device__ __forceinline__ float cvt_f(ushort_t h) {
    return __uint_as_float(((unsigned)h) << 16);
}
__device__ __forceinline__ uchar_t cvt_f8(float f) {
    return (uchar_t)(__builtin_amdgcn_cvt_pk_fp8_f32(f, 0.0f, 0, 0) & 0xff);
}
__device__ __forceinline__ f32x4 mfma16(short8 a, short8 b, f32x4 c) {
    return __builtin_amdgcn_mfma_f32_16x16x32_bf16(a, b, c, 0, 0, 0);
}
__device__ __forceinline__ f32x4 mfma16f8(i64 a, i64 b, f32x4 c) {
    return __builtin_amdgcn_mfma_f32_16x16x32_fp8_fp8(a, b, c, 0, 0, 0);
}
// async global->LDS, 16B per lane; LDS dest = wave-uniform base + lane*16
__device__ __forceinline__ void gld16(const void* g, void* l) {
    __builtin_amdgcn_global_load_lds(
        (const __attribute__((address_space(1))) unsigned int*)g,
        (__attribute__((address_space(3))) unsigned int*)l, 16, 0, 0);
}

// ---------------- K0: weights -> bf16 / fp8 ----------------
__global__ __launch_bounds__(256) void k_prep(const float* __restrict__ f1,
                                              const float* __restrict__ f2,
                                              const float* __restrict__ f3,
                                              const float* __restrict__ opW,
                                              const float* __restrict__ pmw,
                                              const float* __restrict__ pgw,
                                              const float* __restrict__ pow_,
                                              const float* __restrict__ paw,
                                              const float* __restrict__ pbw,
                                              const float* __restrict__ pzw,
                                              ushort_t* __restrict__ f1b,
                                              ushort_t* __restrict__ f2b,
                                              ushort_t* __restrict__ f3b,
                                              uchar_t* __restrict__ opW8,
                                              ushort_t* __restrict__ pmwb,
                                              ushort_t* __restrict__ pgwb,
                                              ushort_t* __restrict__ powb,
                                              ushort_t* __restrict__ abwb,
                                              ushort_t* __restrict__ pzwb) {
    int i = blockIdx.x * 256 + threadIdx.x;      // 131072 threads
    opW8[i] = cvt_f8(opW[i]);
    if (i < FF * DM) {
        f1b[i] = cvt_bf(f1[i]);
        f2b[i] = cvt_bf(f2[i]);
        f3b[i] = cvt_bf(f3[i]);
    }
    if (i < HC * DM) {
        pmwb[i] = cvt_bf(pmw[i]);
        pgwb[i] = cvt_bf(pgw[i]);
        powb[i] = cvt_bf(pow_[i]);
    }
    if (i < 2 * DOP * DM) {                      // combined [64][64]: rows 0..31 paw, 32..63 pbw
        abwb[i] = cvt_bf(i < DOP * DM ? paw[i] : pbw[i - DOP * DM]);
    }
    if (i < 16 * DZ) {                           // [16][128]: rows 0..7 pzw, rows 8..15 zero
        pzwb[i] = (i < NH * DZ) ? cvt_bf(pzw[i]) : (ushort_t)0;
    }
}

// ---------------- K1: fused LN(z) + bias proj + mask + softmax -> wsb (one block per i) ----------------
__global__ __launch_bounds__(256) void k_biassm(const float* __restrict__ z,
                                                const float* __restrict__ nzw,
                                                const float* __restrict__ nzb,
                                                const ushort_t* __restrict__ pzwb,
                                                const float* __restrict__ tmask,
                                                ushort_t* __restrict__ wsb) {
    int i = blockIdx.x;                         // 0..383
    __shared__ ushort_t Azl[128][136];
    __shared__ ushort_t Bl[16][136];
    __shared__ float ob[8][388];
    __shared__ float wln[128], bln[128];
    int t = threadIdx.x;
    if (t < 128) { wln[t] = nzw[t]; bln[t] = nzb[t]; }
    int wave = t >> 6, lane = t & 63;
    int lk = (lane >> 4) * 8, lr = lane & 15;
    int wr = wave * 32;
    // stage B once
    for (int idx = t * 8; idx < 16 * DZ; idx += 256 * 8) {
        int row = idx >> 7, col = idx & 127;
        *(short8*)&Bl[row][col] = *(const short8*)&pzwb[idx];
    }
    __syncthreads();
    for (int c = 0; c < 3; c++) {
        // stage A chunk with fused LN: rows j = c*128 .. +127; 2 threads per row
        {
            int jl = t >> 1, cb = (t & 1) * 64;
            const float* src = &z[((size_t)i * NRES + c * 128 + jl) * DZ + cb];
            float4 v[16];
            float s1 = 0.0f, s2 = 0.0f;
            #pragma unroll
            for (int q = 0; q < 16; q++) {
                v[q] = *(const float4*)&src[q * 4];
                s1 += v[q].x + v[q].y + v[q].z + v[q].w;
                s2 += v[q].x * v[q].x + v[q].y * v[q].y + v[q].z * v[q].z + v[q].w * v[q].w;
            }
            s1 += __shfl_xor(s1, 1, 64);
            s2 += __shfl_xor(s2, 1, 64);
            float mu = s1 * (1.0f / 128.0f);
            float var = s2 * (1.0f / 128.0f) - mu * mu;
            float rs = rsqrtf(var + 1e-5f);
            #pragma unroll
            for (int q = 0; q < 8; q++) {
                float4 xa = v[2 * q], xb = v[2 * q + 1];
                int base = cb + q * 8;
                short8 o;
                o[0] = (short)cvt_bf((xa.x - mu) * rs * wln[base + 0] + bln[base + 0]);
                o[1] = (short)cvt_bf((xa.y - mu) * rs * wln[base + 1] + bln[base + 1]);
                o[2] = (short)cvt_bf((xa.z - mu) * rs * wln[base + 2] + bln[base + 2]);
                o[3] = (short)cvt_bf((xa.w - mu) * rs * wln[base + 3] + bln[base + 3]);
                o[4] = (short)cvt_bf((xb.x - mu) * rs * wln[base + 4] + bln[base + 4]);
                o[5] = (short)cvt_bf((xb.y - mu) * rs * wln[base + 5] + bln[base + 5]);
                o[6] = (short)cvt_bf((xb.z - mu) * rs * wln[base + 6] + bln[base + 6]);
                o[7] = (short)cvt_bf((xb.w - mu) * rs * wln[base + 7] + bln[base + 7]);
                *(short8*)&Azl[jl][base] = o;
            }
        }
        __syncthreads();
        f32x4 acc[2] = {};
        #pragma unroll
        for (int ks = 0; ks < 4; ks++) {
            short8 b = *(const short8*)&Bl[lr][ks * 32 + lk];
            short8 a0 = *(const short8*)&Azl[wr + lr][ks * 32 + lk];
            short8 a1 = *(const short8*)&Azl[wr + 16 + lr][ks * 32 + lk];
            acc[0] = mfma16(a0, b, acc[0]);
            acc[1] = mfma16(a1, b, acc[1]);
        }
        if (lr < NH) {
            #pragma unroll
            for (int ri = 0; ri < 2; ri++) {
                int jb = c * 128 + wr + 16 * ri + (lane >> 4) * 4;
                #pragma unroll
                for (int r = 0; r < 4; r++)
                    ob[lr][jb + r] = acc[ri][r];
            }
        }
        __syncthreads();
    }
    // softmax over j per head (half-wave = one head)
    int h = wave * 2 + (lane >> 5);
    int l32 = lane & 31;
    int jb = l32 * 12;
    const float* tm = &tmask[(size_t)i * NRES];
    float vals[12];
    float mx = -1e30f;
    #pragma unroll
    for (int q = 0; q < 12; q++) {
        float v = ob[h][jb + q] + (1.0f - tm[jb + q]) * (-1e9f);
        vals[q] = v;
        mx = fmaxf(mx, v);
    }
    #pragma unroll
    for (int off = 16; off; off >>= 1) mx = fmaxf(mx, __shfl_xor(mx, off, 64));
    float sum = 0.0f;
    #pragma unroll
    for (int q = 0; q < 12; q++) { vals[q] = expf(vals[q] - mx); sum += vals[q]; }
    #pragma unroll
    for (int off = 16; off; off >>= 1) sum += __shfl_xor(sum, off, 64);
    float inv = 1.0f / sum;
    ushort_t* o = &wsb[(size_t)h * NPAIR + (size_t)i * NRES + jb];
    #pragma unroll
    for (int q = 0; q < 12; q++) o[q] = cvt_bf(vals[q] * inv);
}

// ---------------- K3: LN rows (64-wide) fp32 -> bf16 ----------------
__global__ __launch_bounds__(256) void k_ln64(const float* __restrict__ src,
                                              const float* __restrict__ lw,
                                              const float* __restrict__ lb,
                                              ushort_t* __restrict__ dst) {
    int wave = threadIdx.x >> 6, lane = threadIdx.x & 63;
    int r = blockIdx.x * 4 + wave;
    float x = src[(size_t)r * DM + lane];
    float mu = wred_sum(x) * (1.0f / 64.0f);
    float d = x - mu;
    float var = wred_sum(d * d) * (1.0f / 64.0f);
    dst[(size_t)r * DM + lane] = cvt_bf(d * rsqrtf(var + 1e-5f) * lw[lane] + lb[lane]);
}

// ---------------- K3b: v projection GEMM -> vtt[h][s*32+d][n] directly ----------------
__global__ __launch_bounds__(256) void k_vproj_mfma(const ushort_t* __restrict__ A,
                                                    const ushort_t* __restrict__ Bt,
                                                    ushort_t* __restrict__ vtt) {
    int m0 = blockIdx.y * 64, n0c = blockIdx.x * 64;
    __shared__ ushort_t Al[64][40];
    __shared__ ushort_t Bl[64][40];
    __shared__ ushort_t ot[64][72];
    int t = threadIdx.x;
    int srow = t >> 2, sko = (t & 3) * 8;
    int wave = t >> 6, lane = t & 63;
    int wr = (wave >> 1) * 32, wc = (wave & 1) * 32;
    int lk = (lane >> 4) * 8, lr = lane & 15;
    f32x4 acc[2][2] = {};
    for (int k0 = 0; k0 < DM; k0 += 32) {
        *(short8*)&Al[srow][sko] = *(const short8*)&A[(size_t)(m0 + srow) * DM + k0 + sko];
        *(short8*)&Bl[srow][sko] = *(const short8*)&Bt[(size_t)(n0c + srow) * DM + k0 + sko];
        __syncthreads();
        short8 a0 = *(const short8*)&Al[wr + lr][lk];
        short8 a1 = *(const short8*)&Al[wr + 16 + lr][lk];
        short8 b0 = *(const short8*)&Bl[wc + lr][lk];
        short8 b1 = *(const short8*)&Bl[wc + 16 + lr][lk];
        acc[0][0] = mfma16(a0, b0, acc[0][0]);
        acc[0][1] = mfma16(a0, b1, acc[0][1]);
        acc[1][0] = mfma16(a1, b0, acc[1][0]);
        acc[1][1] = mfma16(a1, b1, acc[1][1]);
        __syncthreads();
    }
    // transpose in LDS: ot[col][row]
    #pragma unroll
    for (int ri = 0; ri < 2; ri++)
        #pragma unroll
        for (int ci = 0; ci < 2; ci++) {
            int rowb = wr + 16 * ri + (lane >> 4) * 4;
            int colb = wc + 16 * ci + lr;
            #pragma unroll
            for (int r = 0; r < 4; r++)
                ot[colb][rowb + r] = cvt_bf(acc[ri][ci][r]);
        }
    __syncthreads();
    int s = m0 / NRES, n0 = m0 % NRES;
    int h0 = n0c >> 5;                          // two heads h0, h0+1
    int orow = t >> 2, seg = (t & 3) * 16;
    short8 v0 = *(const short8*)&ot[orow][seg];
    short8 v1 = *(const short8*)&ot[orow][seg + 8];
    int hh = orow >> 5, dd = orow & 31;
    ushort_t* dst = &vtt[(((size_t)(h0 + hh) * SD) + s * DH + dd) * NRES + n0 + seg];
    *(short8*)&dst[0] = v0;
    *(short8*)&dst[8] = v1;
}

// ---------------- generic 64x64 bf16 transpose ----------------
__global__ __launch_bounds__(256) void k_tr(const ushort_t* __restrict__ src,
                                            ushort_t* __restrict__ dst,
                                            int R, int C) {
    size_t bs = (size_t)R * C;
    const ushort_t* s = src + blockIdx.z * bs;
    ushort_t* d = dst + blockIdx.z * bs;
    int r0 = blockIdx.y * 64, c0 = blockIdx.x * 64;
    __shared__ ushort_t tile[64][72];
    int t = threadIdx.x;
    int tr = t >> 2, tc = (t & 3) * 16;
    *(short8*)&tile[tr][tc]     = *(const short8*)&s[(size_t)(r0 + tr) * C + c0 + tc];
    *(short8*)&tile[tr][tc + 8] = *(const short8*)&s[(size_t)(r0 + tr) * C + c0 + tc + 8];
    __syncthreads();
    short8 o0, o1;
    #pragma unroll
    for (int i = 0; i < 8; i++) {
        o0[i] = (short)tile[tc + i][tr];
        o1[i] = (short)tile[tc + 8 + i][tr];
    }
    *(short8*)&d[(size_t)(c0 + tr) * R + r0 + tc]     = o0;
    *(short8*)&d[(size_t)(c0 + tr) * R + r0 + tc + 8] = o1;
}

// ---------------- K4: attention GEMM per head (128x128 tile, BK=64, XOR-8 swizzle) ----------------
__global__ __launch_bounds__(256) void k_attn_mfma(const ushort_t* __restrict__ wsb,
                                                   const ushort_t* __restrict__ vtt,
                                                   ushort_t* __restrict__ otb2) {
    int h = blockIdx.z;
    const ushort_t* A  = wsb + (size_t)h * NPAIR;        // [384][384]
    const ushort_t* Bt = vtt + (size_t)h * SD * NRES;    // [8192][384]
    int m0 = blockIdx.y * 128, n0 = blockIdx.x * 128;
    __shared__ ushort_t Al[128 * 64];
    __shared__ ushort_t Bl[128 * 64];
    int t = threadIdx.x;
    int w = t >> 6, lane = t & 63;
    int wr = (w >> 1) * 64, wc = (w & 1) * 64;
    int lq = lane >> 4, lr = lane & 15;
    int rS = lane >> 3;                         // 0..7: row within 8-row gld group
    int cqs = (((lane & 7) ^ rS) << 3);         // 8-slot swizzled source col (ushorts)
    f32x4 acc[4][4] = {};
    for (int k0 = 0; k0 < NRES; k0 += 64) {
        #pragma unroll
        for (int g = 0; g < 4; g++) {
            int row = w * 32 + g * 8;           // 4 waves cover 128 rows
            gld16(&A [(size_t)(m0 + row + rS) * NRES + k0 + cqs], &Al[row * 64]);
            gld16(&Bt[(size_t)(n0 + row + rS) * NRES + k0 + cqs], &Bl[row * 64]);
        }
        __syncthreads();
        #pragma unroll
        for (int kk = 0; kk < 2; kk++) {
            short8 af[4], bf2[4];
            #pragma unroll
            for (int i = 0; i < 4; i++) {
                int ra = wr + 16 * i + lr;
                int rb = wc + 16 * i + lr;
                af[i]  = *(const short8*)&Al[ra * 64 + (((kk * 4 + lq) ^ (ra & 7)) << 3)];
                bf2[i] = *(const short8*)&Bl[rb * 64 + (((kk * 4 + lq) ^ (rb & 7)) << 3)];
            }
            #pragma unroll
            for (int ri = 0; ri < 4; ri++)
                #pragma unroll
                for (int ci = 0; ci < 4; ci++)
                    acc[ri][ci] = mfma16(af[ri], bf2[ci], acc[ri][ci]);
        }
        __syncthreads();
    }
    #pragma unroll
    for (int ri = 0; ri < 4; ri++)
        #pragma unroll
        for (int ci = 0; ci < 4; ci++) {
            int row0 = m0 + wr + 16 * ri + (lane >> 4) * 4;   // i
            int col  = n0 + wc + 16 * ci + lr;                // s*32+d
            int s = col >> 5, dd = col & 31;
            #pragma unroll
            for (int r = 0; r < 4; r++)
                otb2[((size_t)s * NRES + row0 + r) * HC + h * DH + dd] = cvt_bf(acc[ri][ci][r]);
        }
}

// ---------------- K5: fused gate GEMM + sigmoid*o + out GEMM + residual + transition-LN -> mout, tn_bf ----------------
__global__ __launch_bounds__(256) void k_gateout(const ushort_t* __restrict__ A,   // mnb [NROWS][64]
                                                 const ushort_t* __restrict__ Bg,  // pgwb [256][64]
                                                 const ushort_t* __restrict__ otb2,// [NROWS][256]
                                                 const ushort_t* __restrict__ Bo,  // powb [64][256]
                                                 const float* __restrict__ m,
                                                 float* __restrict__ mout,
                                                 const float* __restrict__ tnw,
                                                 const float* __restrict__ tnb,
                                                 ushort_t* __restrict__ tn_bf) {
    int m0 = blockIdx.x * 64;
    __shared__ ushort_t Al[64][72];
    __shared__ ushort_t Bl[64][72];
    __shared__ ushort_t go[64][264];
    int t = threadIdx.x;
    int srow = t >> 2, sko = (t & 3) * 16;
    int wave = t >> 6, lane = t & 63;
    int wr = (wave >> 1) * 32, wc = (wave & 1) * 32;
    int lk = (lane >> 4) * 8, lr = lane & 15;
    float tw = tnw[lane], tb = tnb[lane];
    // stage full A tile [64][64]
    {
        const ushort_t* arow = &A[(size_t)(m0 + srow) * DM + sko];
        *(short8*)&Al[srow][sko]     = *(const short8*)&arow[0];
        *(short8*)&Al[srow][sko + 8] = *(const short8*)&arow[8];
    }
    __syncthreads();
    short8 a[2][2];   // [mi][ks]
    a[0][0] = *(const short8*)&Al[wr + lr][lk];
    a[0][1] = *(const short8*)&Al[wr + lr][32 + lk];
    a[1][0] = *(const short8*)&Al[wr + 16 + lr][lk];
    a[1][1] = *(const short8*)&Al[wr + 16 + lr][32 + lk];
    // ---- gate: 4 n-quarters of 64 ----
    for (int nq = 0; nq < 4; nq++) {
        __syncthreads();
        {
            const ushort_t* brow = &Bg[(size_t)(nq * 64 + srow) * DM + sko];
            *(short8*)&Bl[srow][sko]     = *(const short8*)&brow[0];
            *(short8*)&Bl[srow][sko + 8] = *(const short8*)&brow[8];
        }
        __syncthreads();
        f32x4 acc[2][2] = {};
        #pragma unroll
        for (int ks = 0; ks < 2; ks++) {
            short8 b0 = *(const short8*)&Bl[wc + lr][ks * 32 + lk];
            short8 b1 = *(const short8*)&Bl[wc + 16 + lr][ks * 32 + lk];
            acc[0][0] = mfma16(a[0][ks], b0, acc[0][0]);
            acc[0][1] = mfma16(a[0][ks], b1, acc[0][1]);
            acc[1][0] = mfma16(a[1][ks], b0, acc[1][0]);
            acc[1][1] = mfma16(a[1][ks], b1, acc[1][1]);
        }
        #pragma unroll
        for (int ri = 0; ri < 2; ri++)
            #pragma unroll
            for (int ci = 0; ci < 2; ci++) {
                int lrow = wr + 16 * ri + (lane >> 4) * 4;
                int col  = nq * 64 + wc + 16 * ci + lr;
                #pragma unroll
                for (int r = 0; r < 4; r++) {
                    float ov = cvt_f(otb2[(size_t)(m0 + lrow + r) * HC + col]);
                    go[lrow + r][col] = cvt_bf(sigm(acc[ri][ci][r]) * ov);
                }
            }
    }
    // ---- out GEMM: [64 rows][K=256] @ powb^T -> 64 cols, + residual ----
    f32x4 acc[2][2] = {};
    for (int k0 = 0; k0 < HC; k0 += 32) {
        __syncthreads();
        *(short8*)&Bl[t >> 2][(t & 3) * 8] = *(const short8*)&Bo[(size_t)(t >> 2) * HC + k0 + (t & 3) * 8];
        __syncthreads();
        short8 a0 = *(const short8*)&go[wr + lr][k0 + lk];
        short8 a1 = *(const short8*)&go[wr + 16 + lr][k0 + lk];
        short8 b0 = *(const short8*)&Bl[wc + lr][lk];
        short8 b1 = *(const short8*)&Bl[wc + 16 + lr][lk];
        acc[0][0] = mfma16(a0, b0, acc[0][0]);
        acc[0][1] = mfma16(a0, b1, acc[0][1]);
        acc[1][0] = mfma16(a1, b0, acc[1][0]);
        acc[1][1] = mfma16(a1, b1, acc[1][1]);
    }
    __syncthreads();                            // protect go reuse below
    #pragma unroll
    for (int ri = 0; ri < 2; ri++)
        #pragma unroll
        for (int ci = 0; ci < 2; ci++) {
            int lrow0 = wr + 16 * ri + (lane >> 4) * 4;
            int col   = wc + 16 * ci + lr;
            #pragma unroll
            for (int r = 0; r < 4; r++) {
                size_t idx = (size_t)(m0 + lrow0 + r) * DM + col;
                float v = m[idx] + acc[ri][ci][r];
                mout[idx] = v;
                go[lrow0 + r][col] = cvt_bf(v);  // stash for LN
            }
        }
    __syncthreads();
    // ---- transition LN on the 64x64 tile (wave w: rows w*16..w*16+15) ----
    for (int rr = 0; rr < 16; rr++) {
        int row = wave * 16 + rr;
        float x = cvt_f(go[row][lane]);
        float mu = wred_sum(x) * (1.0f / 64.0f);
        float d = x - mu;
        float var = wred_sum(d * d) * (1.0f / 64.0f);
        tn_bf[(size_t)(m0 + row) * DM + lane] = cvt_bf(d * rsqrtf(var + 1e-5f) * tw + tb);
    }
}

// ---------------- K6: fused SwiGLU transition + residual + OPM-LN -> mout, onb_bf ----------------
__global__ __launch_bounds__(256) void k_fctrans(const ushort_t* __restrict__ A,   // tn_bf [NROWS][64]
                                                 const ushort_t* __restrict__ B1,  // f1b [256][64]
                                                 const ushort_t* __restrict__ B2,  // f2b [256][64]
                                                 const ushort_t* __restrict__ B3,  // f3b [64][256]
                                                 float* __restrict__ mio,
                                                 const float* __restrict__ onw,
                                                 const float* __restrict__ onb,
                                                 ushort_t* __restrict__ onb_bf) {
    int m0 = blockIdx.x * 64;
    __shared__ ushort_t Al[64][72];
    __shared__ ushort_t B1l[64][72];
    __shared__ ushort_t B2l[64][72];
    __shared__ ushort_t hhl[64][264];
    int t = threadIdx.x;
    int srow = t >> 2, sko = (t & 3) * 16;
    int wave = t >> 6, lane = t & 63;
    int wr = (wave >> 1) * 32, wc = (wave & 1) * 32;
    int lk = (lane >> 4) * 8, lr = lane & 15;
    float ow = onw[lane], ob = onb[lane];
    {
        const ushort_t* arow = &A[(size_t)(m0 + srow) * DM + sko];
        *(short8*)&Al[srow][sko]     = *(const short8*)&arow[0];
        *(short8*)&Al[srow][sko + 8] = *(const short8*)&arow[8];
    }
    __syncthreads();
    short8 a[2][2];
    a[0][0] = *(const short8*)&Al[wr + lr][lk];
    a[0][1] = *(const short8*)&Al[wr + lr][32 + lk];
    a[1][0] = *(const short8*)&Al[wr + 16 + lr][lk];
    a[1][1] = *(const short8*)&Al[wr + 16 + lr][32 + lk];
    for (int nq = 0; nq < 4; nq++) {
        __syncthreads();
        {
            const ushort_t* b1r = &B1[(size_t)(nq * 64 + srow) * DM + sko];
            const ushort_t* b2r = &B2[(size_t)(nq * 64 + srow) * DM + sko];
            *(short8*)&B1l[srow][sko]     = *(const short8*)&b1r[0];
            *(short8*)&B1l[srow][sko + 8] = *(const short8*)&b1r[8];
            *(short8*)&B2l[srow][sko]     = *(const short8*)&b2r[0];
            *(short8*)&B2l[srow][sko + 8] = *(const short8*)&b2r[8];
        }
        __syncthreads();
        f32x4 acc1[2][2] = {}, acc2[2][2] = {};
        #pragma unroll
        for (int ks = 0; ks < 2; ks++) {
            short8 p0 = *(const short8*)&B1l[wc + lr][ks * 32 + lk];
            short8 p1 = *(const short8*)&B1l[wc + 16 + lr][ks * 32 + lk];
            short8 q0 = *(const short8*)&B2l[wc + lr][ks * 32 + lk];
            short8 q1 = *(const short8*)&B2l[wc + 16 + lr][ks * 32 + lk];
            acc1[0][0] = mfma16(a[0][ks], p0, acc1[0][0]);
            acc1[0][1] = mfma16(a[0][ks], p1, acc1[0][1]);
            acc1[1][0] = mfma16(a[1][ks], p0, acc1[1][0]);
            acc1[1][1] = mfma16(a[1][ks], p1, acc1[1][1]);
            acc2[0][0] = mfma16(a[0][ks], q0, acc2[0][0]);
            acc2[0][1] = mfma16(a[0][ks], q1, acc2[0][1]);
            acc2[1][0] = mfma16(a[1][ks], q0, acc2[1][0]);
            acc2[1][1] = mfma16(a[1][ks], q1, acc2[1][1]);
        }
        #pragma unroll
        for (int ri = 0; ri < 2; ri++)
            #pragma unroll
            for (int ci = 0; ci < 2; ci++) {
                int lrow = wr + 16 * ri + (lane >> 4) * 4;
                int col  = nq * 64 + wc + 16 * ci + lr;
                #pragma unroll
                for (int r = 0; r < 4; r++) {
                    float a1v = acc1[ri][ci][r], a2v = acc2[ri][ci][r];
                    hhl[lrow + r][col] = cvt_bf(a1v * sigm(a1v) * a2v);
                }
            }
    }
    // fc3: [64][256] @ f3b^T -> 64 cols, residual
    f32x4 acc[2][2] = {};
    for (int k0 = 0; k0 < FF; k0 += 32) {
        __syncthreads();
        *(short8*)&B1l[t >> 2][(t & 3) * 8] = *(const short8*)&B3[(size_t)(t >> 2) * FF + k0 + (t & 3) * 8];
        __syncthreads();
        short8 a0 = *(const short8*)&hhl[wr + lr][k0 + lk];
        short8 a1 = *(const short8*)&hhl[wr + 16 + lr][k0 + lk];
        short8 b0 = *(const short8*)&B1l[wc + lr][lk];
        short8 b1 = *(const short8*)&B1l[wc + 16 + lr][lk];
        acc[0][0] = mfma16(a0, b0, acc[0][0]);
        acc[0][1] = mfma16(a0, b1, acc[0][1]);
        acc[1][0] = mfma16(a1, b0, acc[1][0]);
        acc[1][1] = mfma16(a1, b1, acc[1][1]);
    }
    __syncthreads();                            // protect hhl reuse below
    #pragma unroll
    for (int ri = 0; ri < 2; ri++)
        #pragma unroll
        for (int ci = 0; ci < 2; ci++) {
            int lrow0 = wr + 16 * ri + (lane >> 4) * 4;
            int col   = wc + 16 * ci + lr;
            #pragma unroll
            for (int r = 0; r < 4; r++) {
                size_t idx = (size_t)(m0 + lrow0 + r) * DM + col;
                float v = mio[idx] + acc[ri][ci][r];
                mio[idx] = v;
                hhl[lrow0 + r][col] = cvt_bf(v);  // stash for LN
            }
        }
    __syncthreads();
    // ---- OPM LN on the 64x64 tile ----
    for (int rr = 0; rr < 16; rr++) {
        int row = wave * 16 + rr;
        float x = cvt_f(hhl[row][lane]);
        float mu = wred_sum(x) * (1.0f / 64.0f);
        float d = x - mu;
        float var = wred_sum(d * d) * (1.0f / 64.0f);
        onb_bf[(size_t)(m0 + row) * DM + lane] = cvt_bf(d * rsqrtf(var + 1e-5f) * ow + ob);
    }
}

// ---------------- K7: a/b projection GEMM + mask -> abuf/bbuf [s][n*32+c] ----------------
__global__ __launch_bounds__(256) void k_ab_mfma(const ushort_t* __restrict__ A,
                                                 const ushort_t* __restrict__ Bt,
                                                 const float* __restrict__ smask,
                                                 ushort_t* __restrict__ abuf,
                                                 ushort_t* __restrict__ bbuf) {
    int m0 = blockIdx.x * 64;
    __shared__ ushort_t Al[64][40];
    __shared__ ushort_t Bl[64][40];
    int t = threadIdx.x;
    int srow = t >> 2, sko = (t & 3) * 8;
    int wave = t >> 6, lane = t & 63;
    int wr = (wave >> 1) * 32, wc = (wave & 1) * 32;
    int lk = (lane >> 4) * 8, lr = lane & 15;
    f32x4 acc[2][2] = {};
    for (int k0 = 0; k0 < DM; k0 += 32) {
        *(short8*)&Al[srow][sko] = *(const short8*)&A[(size_t)(m0 + srow) * DM + k0 + sko];
        *(short8*)&Bl[srow][sko] = *(const short8*)&Bt[(size_t)srow * DM + k0 + sko];
        __syncthreads();
        short8 a0 = *(const short8*)&Al[wr + lr][lk];
        short8 a1 = *(const short8*)&Al[wr + 16 + lr][lk];
        short8 b0 = *(const short8*)&Bl[wc + lr][lk];
        short8 b1 = *(const short8*)&Bl[wc + 16 + lr][lk];
        acc[0][0] = mfma16(a0, b0, acc[0][0]);
        acc[0][1] = mfma16(a0, b1, acc[0][1]);
        acc[1][0] = mfma16(a1, b0, acc[1][0]);
        acc[1][1] = mfma16(a1, b1, acc[1][1]);
        __syncthreads();
    }
    #pragma unroll
    for (int ri = 0; ri < 2; ri++)
        #pragma unroll
        for (int ci = 0; ci < 2; ci++) {
            int row0 = m0 + wr + 16 * ri + (lane >> 4) * 4;
            int col  = wc + 16 * ci + lr;               // 0..63
            #pragma unroll
            for (int r = 0; r < 4; r++) {
                int rr = row0 + r;                      // s*NRES+n
                int s = rr / NRES, n = rr % NRES;
                float v = acc[ri][ci][r] * smask[rr];
                if (col < DOP)
                    abuf[(size_t)s * (NRES * DOP) + n * DOP + col] = cvt_bf(v);
                else
                    bbuf[(size_t)s * (NRES * DOP) + n * DOP + (col - DOP)] = cvt_bf(v);
            }
        }
}

// ---------------- K8: mask pair-count Gram tile ----------------
__global__ __launch_bounds__(256) void k_msum(const float* __restrict__ smask,
                                              float* __restrict__ msum) {
    int i0 = blockIdx.y * 64, j0 = blockIdx.x * 64;
    __shared__ float As[16][64];
    __shared__ float Bs[16][64];
    int t = threadIdx.x;
    int ty = t >> 4, tx = t & 15;
    float acc[4][4] = {};
    for (int k0 = 0; k0 < NSEQ; k0 += 16) {
        int kk = t >> 4, x4 = (t & 15) * 4;
        *(float4*)&As[kk][x4] = *(const float4*)&smask[(size_t)(k0 + kk) * NRES + i0 + x4];
        *(float4*)&Bs[kk][x4] = *(const float4*)&smask[(size_t)(k0 + kk) * NRES + j0 + x4];
        __syncthreads();
        #pragma unroll
        for (int k = 0; k < 16; k++) {
            float4 a4 = *(const float4*)&As[k][ty * 4];
            float4 b4 = *(const float4*)&Bs[k][tx * 4];
            float ar[4] = {a4.x, a4.y, a4.z, a4.w};
            float br[4] = {b4.x, b4.y, b4.z, b4.w};
            #pragma unroll
            for (int i2 = 0; i2 < 4; i2++)
                #pragma unroll
                for (int j2 = 0; j2 < 4; j2++)
                    acc[i2][j2] += ar[i2] * br[j2];
        }
        __syncthreads();
    }
    #pragma unroll
    for (int r = 0; r < 4; r++) {
        float4 o4 = make_float4(fmaxf(acc[r][0], 1.0f), fmaxf(acc[r][1], 1.0f),
                                fmaxf(acc[r][2], 1.0f), fmaxf(acc[r][3], 1.0f));
        *(float4*)&msum[(size_t)(i0 + ty * 4 + r) * NRES + j0 + tx * 4] = o4;
    }
}

// ---------------- K9: fused OPM outer GEMM + projection + residual -> zout ----------------
// Main loop: opm tile 128x128 (bf16, BK=64, 8-slot swizzle).  Pack fp8 into ol[16][1040].
// Projection: wave-local, K-chunks of 64B (Wl 8KB -> LDS 40KB total -> 4 blocks/CU).
// WAVE-LOCALITY: wave w stages AND reads e-rows [w*32, w*32+32) (row = w*32 + g*16).
__global__ __launch_bounds__(256) void k_opm_mfma(const ushort_t* __restrict__ At,
                                                  const ushort_t* __restrict__ Bt,
                                                  const uchar_t* __restrict__ opW8,
                                                  const float* __restrict__ opB,
                                                  const float* __restrict__ msum,
                                                  const float* __restrict__ zin,
                                                  float* __restrict__ zout,
                                                  int ib) {
    int m0 = blockIdx.y * 128;                  // over ichunk*32 (il,c)
    int n0 = blockIdx.x * 128;                  // over 12288 (j,d)
    __shared__ ushort_t ABl[2 * 128 * 64];      // Al | Bl contiguous; ol alias spans both
    __shared__ uchar_t Wl[128 * 64];            // 8KB W chunk (64B of K per e-row)
    ushort_t* Al = ABl;
    ushort_t* Bl = ABl + 128 * 64;
    uchar_t* ol = (uchar_t*)ABl;                // 16*1040 = 16640B, safe within 32KB ABl
    int t = threadIdx.x;
    int w = t >> 6, lane = t & 63;
    int wr = (w >> 1) * 64, wc = (w & 1) * 64;
    int lq = lane >> 4, lr = lane & 15;
    int rS = lane >> 3;                         // 0..7: row within 8-row gld group
    int cqs = (((lane & 7) ^ rS) << 3);         // 8-slot swizzled source col (ushorts)
    int rS16 = lane >> 2, sl4 = lane & 3;       // 16-row gld group for 64B W rows
    int cW = ((sl4 ^ (rS16 & 3)) << 4);         // 4-slot swizzled source col (bytes)
    f32x4 acc[4][4] = {};                       // rows<-n (quad), cols<-m (lr), swapped
    for (int k0 = 0; k0 < NSEQ; k0 += 64) {
        #pragma unroll
        for (int g = 0; g < 4; g++) {
            int row = w * 32 + g * 8;           // 4 waves cover 128 rows
            gld16(&At[(size_t)(m0 + row + rS) * NSEQ + k0 + cqs], &Al[row * 64]);
            gld16(&Bt[(size_t)(n0 + row + rS) * NSEQ + k0 + cqs], &Bl[row * 64]);
        }
        __syncthreads();
        #pragma unroll
        for (int kk = 0; kk < 2; kk++) {
            short8 af[4], bf2[4];
            #pragma unroll
            for (int i = 0; i < 4; i++) {
                int ra = wr + 16 * i + lr;
                int rb = wc + 16 * i + lr;
                af[i]  = *(const short8*)&Al[ra * 64 + (((kk * 4 + lq) ^ (ra & 7)) << 3)];
                bf2[i] = *(const short8*)&Bl[rb * 64 + (((kk * 4 + lq) ^ (rb & 7)) << 3)];
            }
            #pragma unroll
            for (int ri = 0; ri < 4; ri++)
                #pragma unroll
                for (int ci = 0; ci < 4; ci++)
                    acc[ri][ci] = mfma16(bf2[ci], af[ri], acc[ri][ci]);   // swapped
        }
        __syncthreads();
    }
    // prefetch W chunk 0: wave w stages its OWN e-rows [w*32, w*32+32) (2 gld16 x 16 rows)
    #pragma unroll
    for (int g = 0; g < 2; g++) {
        int row = w * 32 + g * 16;
        gld16(&opW8[(size_t)(row + rS16) * 1024 + cW], &Wl[row * 64]);
    }
    // pack fp8 quads into ol (overwrites Al/Bl region, all reads done): row p = il*4+j, byte (c<<5)+dd
    #pragma unroll
    for (int ri = 0; ri < 4; ri++)
        #pragma unroll
        for (int ci = 0; ci < 4; ci++) {
            int ml = wr + 16 * ri + lr;                   // local (il,c)
            int il = ml >> 5, c = ml & 31;
            int nl = wc + 16 * ci + lq * 4;               // local (j,dd), dd quad-aligned
            int j = nl >> 5, dd = nl & 31;
            int p = il * 4 + j;
            int p01  = __builtin_amdgcn_cvt_pk_fp8_f32(acc[ri][ci][0], acc[ri][ci][1], 0, 0);
            int pall = __builtin_amdgcn_cvt_pk_fp8_f32(acc[ri][ci][2], acc[ri][ci][3], p01, 1);
            *(int*)&ol[p * 1040 + (c << 5) + dd] = pall;
        }
    __syncthreads();                            // ol visible to all waves
    // ---- projection (wave-local): out[p=16][e=128] = ol[16][K=1024] @ opW8^T, 16 chunks of 64 ----
    f32x4 accp[2] = {};                         // wave w covers e in [w*32, w*32+32)
    for (int kc = 0; kc < 16; kc++) {
        asm volatile("s_waitcnt vmcnt(0)" ::: "memory");   // wave's Wl chunk landed
        __builtin_amdgcn_sched_barrier(0);
        // read ALL fragments of this chunk into registers (2 k-slices of 32)
        i64 afr[2], bfr[2][2];
        #pragma unroll
        for (int ls = 0; ls < 2; ls++) {
            int l = ls * 2 + (lq >> 1);         // logical 16B slot within 64B row
            int wo = (lq & 1) * 8;
            afr[ls] = *(const i64*)&ol[lr * 1040 + kc * 64 + ls * 32 + lq * 8];
            #pragma unroll
            for (int et = 0; et < 2; et++) {
                int er = w * 32 + et * 16 + lr;
                bfr[ls][et] = *(const i64*)&Wl[er * 64 + ((l ^ (er & 3)) << 4) + wo];
            }
        }
        if (kc < 15) {
            asm volatile("s_waitcnt lgkmcnt(0)" ::: "memory");  // frags in regs; Wl free
            __builtin_amdgcn_sched_barrier(0);
            #pragma unroll
            for (int g = 0; g < 2; g++) {
                int row = w * 32 + g * 16;
                gld16(&opW8[(size_t)(row + rS16) * 1024 + (kc + 1) * 64 + cW], &Wl[row * 64]);
            }
        }
        #pragma unroll
        for (int ls = 0; ls < 2; ls++)
            #pragma unroll
            for (int et = 0; et < 2; et++)
                accp[et] = mfma16f8(bfr[ls][et], afr[ls], accp[et]);   // quad<-e, lr<-p
    }
    // epilogue: z residual + bias + /msum
    {
        int p = lr;
        int ilg = ib + (m0 >> 5) + (p >> 2);
        int jg  = (n0 >> 5) + (p & 3);
        size_t G = (size_t)ilg * NRES + jg;
        float inv = 1.0f / msum[G];
        #pragma unroll
        for (int et = 0; et < 2; et++) {
            int e0 = w * 32 + et * 16 + lq * 4;
            float4 zv = *(const float4*)&zin[G * DZ + e0];
            float4 bv = *(const float4*)&opB[e0];
            float4 o4;
            o4.x = zv.x + accp[et][0] * inv + bv.x;
            o4.y = zv.y + accp[et][1] * inv + bv.y;
            o4.z = zv.z + accp[et][2] * inv + bv.z;
            o4.w = zv.w + accp[et][3] * inv + bv.w;
            *(float4*)&zout[G * DZ + e0] = o4;
        }
    }
}

// ---------------- launch ----------------
extern "C" void kernel_launch(void* const* d_in, const int* in_sizes, int n_in,
                              void* d_out, int out_size, void* d_ws, size_t ws_size,
                              hipStream_t stream) {
    const float* z     = (const float*)d_in[0];
    const float* m     = (const float*)d_in[1];
    const float* tmask = (const float*)d_in[2];
    const float* smask = (const float*)d_in[3];
    const float* nzw   = (const float*)d_in[4];
    const float* nzb   = (const float*)d_in[5];
    const float* pzw   = (const float*)d_in[6];
    const float* nmw   = (const float*)d_in[7];
    const float* nmb   = (const float*)d_in[8];
    const float* pmw   = (const float*)d_in[9];
    const float* pgw   = (const float*)d_in[10];
    const float* pow_  = (const float*)d_in[11];
    const float* tnw   = (const float*)d_in[12];
    const float* tnb_  = (const float*)d_in[13];
    const float* f1    = (const float*)d_in[14];
    const float* f2    = (const float*)d_in[15];
    const float* f3    = (const float*)d_in[16];
    const float* onw   = (const float*)d_in[17];
    const float* onb   = (const float*)d_in[18];
    const float* paw   = (const float*)d_in[19];
    const float* pbw   = (const float*)d_in[20];
    const float* opW   = (const float*)d_in[21];
    const float* opB   = (const float*)d_in[22];

    float* zout = (float*)d_out;
    float* mout = zout + ZTOT;

    char* W = (char*)d_ws;
    // fixed low region
    ushort_t* wsb  = (ushort_t*)(W + 4718592);          //  .. 7,077,888 (bf16 softmax wts)
    ushort_t* mnb  = (ushort_t*)(W + 7077888);          //  .. 19,660,800 (12.6MB)
    ushort_t* vtt  = (ushort_t*)(W + 69992448);         //  .. 120,324,096 (50.3MB)
    ushort_t* otb2 = (ushort_t*)(W + 120324096);        //  .. 170,655,744 (50.3MB)
    // aliases in low region
    ushort_t* tn_bf  = vtt;                 // vtt dead after k_attn_mfma
    ushort_t* onb_bf = mnb;                 // mnb dead after k_gateout
    ushort_t* abuf = (ushort_t*)(W + 69992448 + 12582912);   // vtt+12.6MB (dead after k_tr)
    ushort_t* bbuf = (ushort_t*)(W + 69992448 + 18874368);   // vtt+18.9MB

    // OPM layout: single-pass if workspace is large enough (ws=384MiB observed),
    // else proven 4-chunk fallback. Projection is fused into k_opm (no opmc intermediate).
    bool big = ws_size >= 348200000ull;
    int ichunk, nchunks;
    uchar_t *opW8;
    ushort_t *abt, *bbt;
    float* msum;
    ushort_t *f1b, *f2b, *f3b, *pmwb, *pgwb, *powb, *abwb, *pzwb;
    if (big) {
        ichunk = NRES; nchunks = 1;
        abt  = (ushort_t*)(W + 321650688);              // 6.29MB  .. 327,942,144
        bbt  = (ushort_t*)(W + 327942144);              // 6.29MB  .. 334,233,600 (= abt + R*C, matches k_tr z-stride)
        msum = (float*)(W + 346816512);                 // 0.59MB  .. 347,406,336
        f1b  = (ushort_t*)(W + 347406336);
        f2b  = (ushort_t*)(W + 347439104);
        f3b  = (ushort_t*)(W + 347471872);
        opW8 = (uchar_t*)(W + 347504640);               // 131,072 B (fp8)
        pmwb = (ushort_t*)(W + 347766784);
        pgwb = (ushort_t*)(W + 347799552);
        powb = (ushort_t*)(W + 347832320);
        abwb = (ushort_t*)(W + 347865088);
        pzwb = (ushort_t*)(W + 347873280);              // .. 347,877,376
    } else {
        ichunk = 96; nchunks = 4;
        abt  = otb2;                                    // otb2 dead after k_gateout
        bbt  = (ushort_t*)(W + 120324096 + 6291456);
        msum = (float*)(W + 170655744);
        f1b  = (ushort_t*)(W + 171245568);
        f2b  = (ushort_t*)(W + 171278336);
        f3b  = (ushort_t*)(W + 171311104);
        opW8 = (uchar_t*)(W + 171343872);               // 131,072 B (fp8)
        pmwb = (ushort_t*)(W + 171606016);
        pgwb = (ushort_t*)(W + 171638784);
        powb = (ushort_t*)(W + 171671552);
        abwb = (ushort_t*)(W + 171704320);
        pzwb = (ushort_t*)(W + 171712512);
    }

    k_prep<<<512, 256, 0, stream>>>(f1, f2, f3, opW, pmw, pgw, pow_, paw, pbw, pzw,
                                    f1b, f2b, f3b, opW8, pmwb, pgwb, powb, abwb, pzwb);

    // PairWeightedAveraging
    k_biassm<<<NRES, 256, 0, stream>>>(z, nzw, nzb, pzwb, tmask, wsb);
    k_ln64<<<NROWS / 4, 256, 0, stream>>>(m, nmw, nmb, mnb);
    k_vproj_mfma<<<dim3(HC / 64, NROWS / 64), 256, 0, stream>>>(mnb, pmwb, vtt);
    k_attn_mfma<<<dim3(SD / 128, NRES / 128, NH), 256, 0, stream>>>(wsb, vtt, otb2);
    k_gateout<<<NROWS / 64, 256, 0, stream>>>(mnb, pgwb, otb2, powb, m, mout, tnw, tnb_, tn_bf);

    // Transition (fused, also emits OPM LN)
    k_fctrans<<<NROWS / 64, 256, 0, stream>>>(tn_bf, f1b, f2b, f3b, mout, onw, onb, onb_bf);

    // OuterProductMean (fused outer GEMM + projection)
    k_ab_mfma<<<NROWS / 64, 256, 0, stream>>>(onb_bf, abwb, smask, abuf, bbuf);
    k_tr<<<dim3((NRES * DOP) / 64, NSEQ / 64, 2), 256, 0, stream>>>(abuf, abt, NSEQ, NRES * DOP);
    k_msum<<<dim3(NRES / 64, NRES / 64), 256, 0, stream>>>(smask, msum);
    for (int cb = 0; cb < nchunks; cb++) {
        int ib = cb * ichunk;
        const ushort_t* Achunk = abt + (size_t)(ib * DOP) * NSEQ;
        k_opm_mfma<<<dim3((NRES * DOP) / 128, (ichunk * DOP) / 128), 256, 0, stream>>>(
            Achunk, bbt, opW8, opB, msum, z, zout, ib);
    }
}

// Round 32
// 399.914 us; speedup vs baseline: 1.0777x; 1.0777x over previous
//
#include <hip/hip_runtime.h>
#include <math.h>

// ---------------- problem constants ----------------
constexpr int NRES = 384;          // N
constexpr int NSEQ = 256;          // S
constexpr int DM   = 64;           // MSA_S
constexpr int DZ   = 128;          // Z_D
constexpr int NH   = 8;            // H
constexpr int DH   = 32;           // C_H
constexpr int HC   = NH * DH;      // 256
constexpr int DOP  = 32;           // C_OPM
constexpr int FF   = 4 * DM;       // 256

constexpr int NPAIR = NRES * NRES;         // 147456
constexpr int NROWS = NSEQ * NRES;         // 98304
constexpr int ZTOT  = NPAIR * DZ;          // 18874368
constexpr int SD    = NSEQ * DH;           // 8192

typedef unsigned short ushort_t;
typedef unsigned char uchar_t;
typedef long long i64;
typedef __attribute__((ext_vector_type(8))) short short8;
typedef __attribute__((ext_vector_type(4))) float f32x4;
typedef __attribute__((ext_vector_type(4))) int int4_t;

__device__ __forceinline__ float wred_sum(float v) {
    #pragma unroll
    for (int off = 32; off; off >>= 1) v += __shfl_xor(v, off, 64);
    return v;
}
__device__ __forceinline__ float sigm(float x) { return 1.0f / (1.0f + expf(-x)); }
__device__ __forceinline__ ushort_t cvt_bf(float f) {
    unsigned u = __float_as_uint(f);
    unsigned r = (u + 0x7FFFu + ((u >> 16) & 1u)) >> 16;
    return (ushort_t)r;
}
__device__ __forceinline__ float cvt_f(ushort_t h) {
    return __uint_as_float(((unsigned)h) << 16);
}
__device__ __forceinline__ uchar_t cvt_f8(float f) {
    return (uchar_t)(__builtin_amdgcn_cvt_pk_fp8_f32(f, 0.0f, 0, 0) & 0xff);
}
__device__ __forceinline__ f32x4 mfma16(short8 a, short8 b, f32x4 c) {
    return __builtin_amdgcn_mfma_f32_16x16x32_bf16(a, b, c, 0, 0, 0);
}
__device__ __forceinline__ f32x4 mfma16f8(i64 a, i64 b, f32x4 c) {
    return __builtin_amdgcn_mfma_f32_16x16x32_fp8_fp8(a, b, c, 0, 0, 0);
}
// async global->LDS, 16B per lane; LDS dest = wave-uniform base + lane*16
__device__ __forceinline__ void gld16(const void* g, void* l) {
    __builtin_amdgcn_global_load_lds(
        (const __attribute__((address_space(1))) unsigned int*)g,
        (__attribute__((address_space(3))) unsigned int*)l, 16, 0, 0);
}

// ---------------- K0: weights -> bf16 / fp8 ----------------
__global__ __launch_bounds__(256) void k_prep(const float* __restrict__ f1,
                                              const float* __restrict__ f2,
                                              const float* __restrict__ f3,
                                              const float* __restrict__ opW,
                                              const float* __restrict__ pmw,
                                              const float* __restrict__ pgw,
                                              const float* __restrict__ pow_,
                                              const float* __restrict__ paw,
                                              const float* __restrict__ pbw,
                                              const float* __restrict__ pzw,
                                              ushort_t* __restrict__ f1b,
                                              ushort_t* __restrict__ f2b,
                                              ushort_t* __restrict__ f3b,
                                              uchar_t* __restrict__ opW8,
                                              ushort_t* __restrict__ pmwb,
                                              ushort_t* __restrict__ pgwb,
                                              ushort_t* __restrict__ powb,
                                              ushort_t* __restrict__ abwb,
                                              ushort_t* __restrict__ pzwb) {
    int i = blockIdx.x * 256 + threadIdx.x;      // 131072 threads
    opW8[i] = cvt_f8(opW[i]);
    if (i < FF * DM) {
        f1b[i] = cvt_bf(f1[i]);
        f2b[i] = cvt_bf(f2[i]);
        f3b[i] = cvt_bf(f3[i]);
    }
    if (i < HC * DM) {
        pmwb[i] = cvt_bf(pmw[i]);
        pgwb[i] = cvt_bf(pgw[i]);
        powb[i] = cvt_bf(pow_[i]);
    }
    if (i < 2 * DOP * DM) {                      // combined [64][64]: rows 0..31 paw, 32..63 pbw
        abwb[i] = cvt_bf(i < DOP * DM ? paw[i] : pbw[i - DOP * DM]);
    }
    if (i < 16 * DZ) {                           // [16][128]: rows 0..7 pzw, rows 8..15 zero
        pzwb[i] = (i < NH * DZ) ? cvt_bf(pzw[i]) : (ushort_t)0;
    }
}

// ---------------- K1: fused LN(z) + bias proj + mask + softmax -> wsb (one block per i) ----------------
__global__ __launch_bounds__(256) void k_biassm(const float* __restrict__ z,
                                                const float* __restrict__ nzw,
                                                const float* __restrict__ nzb,
                                                const ushort_t* __restrict__ pzwb,
                                                const float* __restrict__ tmask,
                                                ushort_t* __restrict__ wsb) {
    int i = blockIdx.x;                         // 0..383
    __shared__ ushort_t Azl[128][136];
    __shared__ ushort_t Bl[16][136];
    __shared__ float ob[8][388];
    __shared__ float wln[128], bln[128];
    int t = threadIdx.x;
    if (t < 128) { wln[t] = nzw[t]; bln[t] = nzb[t]; }
    int wave = t >> 6, lane = t & 63;
    int lk = (lane >> 4) * 8, lr = lane & 15;
    int wr = wave * 32;
    // stage B once
    for (int idx = t * 8; idx < 16 * DZ; idx += 256 * 8) {
        int row = idx >> 7, col = idx & 127;
        *(short8*)&Bl[row][col] = *(const short8*)&pzwb[idx];
    }
    __syncthreads();
    for (int c = 0; c < 3; c++) {
        // stage A chunk with fused LN: rows j = c*128 .. +127; 2 threads per row
        {
            int jl = t >> 1, cb = (t & 1) * 64;
            const float* src = &z[((size_t)i * NRES + c * 128 + jl) * DZ + cb];
            float4 v[16];
            float s1 = 0.0f, s2 = 0.0f;
            #pragma unroll
            for (int q = 0; q < 16; q++) {
                v[q] = *(const float4*)&src[q * 4];
                s1 += v[q].x + v[q].y + v[q].z + v[q].w;
                s2 += v[q].x * v[q].x + v[q].y * v[q].y + v[q].z * v[q].z + v[q].w * v[q].w;
            }
            s1 += __shfl_xor(s1, 1, 64);
            s2 += __shfl_xor(s2, 1, 64);
            float mu = s1 * (1.0f / 128.0f);
            float var = s2 * (1.0f / 128.0f) - mu * mu;
            float rs = rsqrtf(var + 1e-5f);
            #pragma unroll
            for (int q = 0; q < 8; q++) {
                float4 xa = v[2 * q], xb = v[2 * q + 1];
                int base = cb + q * 8;
                short8 o;
                o[0] = (short)cvt_bf((xa.x - mu) * rs * wln[base + 0] + bln[base + 0]);
                o[1] = (short)cvt_bf((xa.y - mu) * rs * wln[base + 1] + bln[base + 1]);
                o[2] = (short)cvt_bf((xa.z - mu) * rs * wln[base + 2] + bln[base + 2]);
                o[3] = (short)cvt_bf((xa.w - mu) * rs * wln[base + 3] + bln[base + 3]);
                o[4] = (short)cvt_bf((xb.x - mu) * rs * wln[base + 4] + bln[base + 4]);
                o[5] = (short)cvt_bf((xb.y - mu) * rs * wln[base + 5] + bln[base + 5]);
                o[6] = (short)cvt_bf((xb.z - mu) * rs * wln[base + 6] + bln[base + 6]);
                o[7] = (short)cvt_bf((xb.w - mu) * rs * wln[base + 7] + bln[base + 7]);
                *(short8*)&Azl[jl][base] = o;
            }
        }
        __syncthreads();
        f32x4 acc[2] = {};
        #pragma unroll
        for (int ks = 0; ks < 4; ks++) {
            short8 b = *(const short8*)&Bl[lr][ks * 32 + lk];
            short8 a0 = *(const short8*)&Azl[wr + lr][ks * 32 + lk];
            short8 a1 = *(const short8*)&Azl[wr + 16 + lr][ks * 32 + lk];
            acc[0] = mfma16(a0, b, acc[0]);
            acc[1] = mfma16(a1, b, acc[1]);
        }
        if (lr < NH) {
            #pragma unroll
            for (int ri = 0; ri < 2; ri++) {
                int jb = c * 128 + wr + 16 * ri + (lane >> 4) * 4;
                #pragma unroll
                for (int r = 0; r < 4; r++)
                    ob[lr][jb + r] = acc[ri][r];
            }
        }
        __syncthreads();
    }
    // softmax over j per head (half-wave = one head)
    int h = wave * 2 + (lane >> 5);
    int l32 = lane & 31;
    int jb = l32 * 12;
    const float* tm = &tmask[(size_t)i * NRES];
    float vals[12];
    float mx = -1e30f;
    #pragma unroll
    for (int q = 0; q < 12; q++) {
        float v = ob[h][jb + q] + (1.0f - tm[jb + q]) * (-1e9f);
        vals[q] = v;
        mx = fmaxf(mx, v);
    }
    #pragma unroll
    for (int off = 16; off; off >>= 1) mx = fmaxf(mx, __shfl_xor(mx, off, 64));
    float sum = 0.0f;
    #pragma unroll
    for (int q = 0; q < 12; q++) { vals[q] = expf(vals[q] - mx); sum += vals[q]; }
    #pragma unroll
    for (int off = 16; off; off >>= 1) sum += __shfl_xor(sum, off, 64);
    float inv = 1.0f / sum;
    ushort_t* o = &wsb[(size_t)h * NPAIR + (size_t)i * NRES + jb];
    #pragma unroll
    for (int q = 0; q < 12; q++) o[q] = cvt_bf(vals[q] * inv);
}

// ---------------- K3: LN rows (64-wide) fp32 -> bf16 ----------------
__global__ __launch_bounds__(256) void k_ln64(const float* __restrict__ src,
                                              const float* __restrict__ lw,
                                              const float* __restrict__ lb,
                                              ushort_t* __restrict__ dst) {
    int wave = threadIdx.x >> 6, lane = threadIdx.x & 63;
    int r = blockIdx.x * 4 + wave;
    float x = src[(size_t)r * DM + lane];
    float mu = wred_sum(x) * (1.0f / 64.0f);
    float d = x - mu;
    float var = wred_sum(d * d) * (1.0f / 64.0f);
    dst[(size_t)r * DM + lane] = cvt_bf(d * rsqrtf(var + 1e-5f) * lw[lane] + lb[lane]);
}

// ---------------- K3b: v projection GEMM -> vtt[h][s*32+d][n] directly ----------------
__global__ __launch_bounds__(256) void k_vproj_mfma(const ushort_t* __restrict__ A,
                                                    const ushort_t* __restrict__ Bt,
                                                    ushort_t* __restrict__ vtt) {
    int m0 = blockIdx.y * 64, n0c = blockIdx.x * 64;
    __shared__ ushort_t Al[64][40];
    __shared__ ushort_t Bl[64][40];
    __shared__ ushort_t ot[64][72];
    int t = threadIdx.x;
    int srow = t >> 2, sko = (t & 3) * 8;
    int wave = t >> 6, lane = t & 63;
    int wr = (wave >> 1) * 32, wc = (wave & 1) * 32;
    int lk = (lane >> 4) * 8, lr = lane & 15;
    f32x4 acc[2][2] = {};
    for (int k0 = 0; k0 < DM; k0 += 32) {
        *(short8*)&Al[srow][sko] = *(const short8*)&A[(size_t)(m0 + srow) * DM + k0 + sko];
        *(short8*)&Bl[srow][sko] = *(const short8*)&Bt[(size_t)(n0c + srow) * DM + k0 + sko];
        __syncthreads();
        short8 a0 = *(const short8*)&Al[wr + lr][lk];
        short8 a1 = *(const short8*)&Al[wr + 16 + lr][lk];
        short8 b0 = *(const short8*)&Bl[wc + lr][lk];
        short8 b1 = *(const short8*)&Bl[wc + 16 + lr][lk];
        acc[0][0] = mfma16(a0, b0, acc[0][0]);
        acc[0][1] = mfma16(a0, b1, acc[0][1]);
        acc[1][0] = mfma16(a1, b0, acc[1][0]);
        acc[1][1] = mfma16(a1, b1, acc[1][1]);
        __syncthreads();
    }
    // transpose in LDS: ot[col][row]
    #pragma unroll
    for (int ri = 0; ri < 2; ri++)
        #pragma unroll
        for (int ci = 0; ci < 2; ci++) {
            int rowb = wr + 16 * ri + (lane >> 4) * 4;
            int colb = wc + 16 * ci + lr;
            #pragma unroll
            for (int r = 0; r < 4; r++)
                ot[colb][rowb + r] = cvt_bf(acc[ri][ci][r]);
        }
    __syncthreads();
    int s = m0 / NRES, n0 = m0 % NRES;
    int h0 = n0c >> 5;                          // two heads h0, h0+1
    int orow = t >> 2, seg = (t & 3) * 16;
    short8 v0 = *(const short8*)&ot[orow][seg];
    short8 v1 = *(const short8*)&ot[orow][seg + 8];
    int hh = orow >> 5, dd = orow & 31;
    ushort_t* dst = &vtt[(((size_t)(h0 + hh) * SD) + s * DH + dd) * NRES + n0 + seg];
    *(short8*)&dst[0] = v0;
    *(short8*)&dst[8] = v1;
}

// ---------------- generic 64x64 bf16 transpose ----------------
__global__ __launch_bounds__(256) void k_tr(const ushort_t* __restrict__ src,
                                            ushort_t* __restrict__ dst,
                                            int R, int C) {
    size_t bs = (size_t)R * C;
    const ushort_t* s = src + blockIdx.z * bs;
    ushort_t* d = dst + blockIdx.z * bs;
    int r0 = blockIdx.y * 64, c0 = blockIdx.x * 64;
    __shared__ ushort_t tile[64][72];
    int t = threadIdx.x;
    int tr = t >> 2, tc = (t & 3) * 16;
    *(short8*)&tile[tr][tc]     = *(const short8*)&s[(size_t)(r0 + tr) * C + c0 + tc];
    *(short8*)&tile[tr][tc + 8] = *(const short8*)&s[(size_t)(r0 + tr) * C + c0 + tc + 8];
    __syncthreads();
    short8 o0, o1;
    #pragma unroll
    for (int i = 0; i < 8; i++) {
        o0[i] = (short)tile[tc + i][tr];
        o1[i] = (short)tile[tc + 8 + i][tr];
    }
    *(short8*)&d[(size_t)(c0 + tr) * R + r0 + tc]     = o0;
    *(short8*)&d[(size_t)(c0 + tr) * R + r0 + tc + 8] = o1;
}

// ---------------- K4: attention GEMM per head (128x128 tile, BK=64, XOR-8 swizzle) ----------------
__global__ __launch_bounds__(256) void k_attn_mfma(const ushort_t* __restrict__ wsb,
                                                   const ushort_t* __restrict__ vtt,
                                                   ushort_t* __restrict__ otb2) {
    int h = blockIdx.z;
    const ushort_t* A  = wsb + (size_t)h * NPAIR;        // [384][384]
    const ushort_t* Bt = vtt + (size_t)h * SD * NRES;    // [8192][384]
    int m0 = blockIdx.y * 128, n0 = blockIdx.x * 128;
    __shared__ ushort_t Al[128 * 64];
    __shared__ ushort_t Bl[128 * 64];
    int t = threadIdx.x;
    int w = t >> 6, lane = t & 63;
    int wr = (w >> 1) * 64, wc = (w & 1) * 64;
    int lq = lane >> 4, lr = lane & 15;
    int rS = lane >> 3;                         // 0..7: row within 8-row gld group
    int cqs = (((lane & 7) ^ rS) << 3);         // 8-slot swizzled source col (ushorts)
    f32x4 acc[4][4] = {};
    for (int k0 = 0; k0 < NRES; k0 += 64) {
        #pragma unroll
        for (int g = 0; g < 4; g++) {
            int row = w * 32 + g * 8;           // 4 waves cover 128 rows
            gld16(&A [(size_t)(m0 + row + rS) * NRES + k0 + cqs], &Al[row * 64]);
            gld16(&Bt[(size_t)(n0 + row + rS) * NRES + k0 + cqs], &Bl[row * 64]);
        }
        __syncthreads();
        #pragma unroll
        for (int kk = 0; kk < 2; kk++) {
            short8 af[4], bf2[4];
            #pragma unroll
            for (int i = 0; i < 4; i++) {
                int ra = wr + 16 * i + lr;
                int rb = wc + 16 * i + lr;
                af[i]  = *(const short8*)&Al[ra * 64 + (((kk * 4 + lq) ^ (ra & 7)) << 3)];
                bf2[i] = *(const short8*)&Bl[rb * 64 + (((kk * 4 + lq) ^ (rb & 7)) << 3)];
            }
            #pragma unroll
            for (int ri = 0; ri < 4; ri++)
                #pragma unroll
                for (int ci = 0; ci < 4; ci++)
                    acc[ri][ci] = mfma16(af[ri], bf2[ci], acc[ri][ci]);
        }
        __syncthreads();
    }
    #pragma unroll
    for (int ri = 0; ri < 4; ri++)
        #pragma unroll
        for (int ci = 0; ci < 4; ci++) {
            int row0 = m0 + wr + 16 * ri + (lane >> 4) * 4;   // i
            int col  = n0 + wc + 16 * ci + lr;                // s*32+d
            int s = col >> 5, dd = col & 31;
            #pragma unroll
            for (int r = 0; r < 4; r++)
                otb2[((size_t)s * NRES + row0 + r) * HC + h * DH + dd] = cvt_bf(acc[ri][ci][r]);
        }
}

// ---------------- K5: fused gate GEMM + sigmoid*o + out GEMM + residual + transition-LN -> mout, tn_bf ----------------
__global__ __launch_bounds__(256) void k_gateout(const ushort_t* __restrict__ A,   // mnb [NROWS][64]
                                                 const ushort_t* __restrict__ Bg,  // pgwb [256][64]
                                                 const ushort_t* __restrict__ otb2,// [NROWS][256]
                                                 const ushort_t* __restrict__ Bo,  // powb [64][256]
                                                 const float* __restrict__ m,
                                                 float* __restrict__ mout,
                                                 const float* __restrict__ tnw,
                                                 const float* __restrict__ tnb,
                                                 ushort_t* __restrict__ tn_bf) {
    int m0 = blockIdx.x * 64;
    __shared__ ushort_t Al[64][72];
    __shared__ ushort_t Bl[64][72];
    __shared__ ushort_t go[64][264];
    int t = threadIdx.x;
    int srow = t >> 2, sko = (t & 3) * 16;
    int wave = t >> 6, lane = t & 63;
    int wr = (wave >> 1) * 32, wc = (wave & 1) * 32;
    int lk = (lane >> 4) * 8, lr = lane & 15;
    float tw = tnw[lane], tb = tnb[lane];
    // stage full A tile [64][64]
    {
        const ushort_t* arow = &A[(size_t)(m0 + srow) * DM + sko];
        *(short8*)&Al[srow][sko]     = *(const short8*)&arow[0];
        *(short8*)&Al[srow][sko + 8] = *(const short8*)&arow[8];
    }
    __syncthreads();
    short8 a[2][2];   // [mi][ks]
    a[0][0] = *(const short8*)&Al[wr + lr][lk];
    a[0][1] = *(const short8*)&Al[wr + lr][32 + lk];
    a[1][0] = *(const short8*)&Al[wr + 16 + lr][lk];
    a[1][1] = *(const short8*)&Al[wr + 16 + lr][32 + lk];
    // ---- gate: 4 n-quarters of 64 ----
    for (int nq = 0; nq < 4; nq++) {
        __syncthreads();
        {
            const ushort_t* brow = &Bg[(size_t)(nq * 64 + srow) * DM + sko];
            *(short8*)&Bl[srow][sko]     = *(const short8*)&brow[0];
            *(short8*)&Bl[srow][sko + 8] = *(const short8*)&brow[8];
        }
        __syncthreads();
        f32x4 acc[2][2] = {};
        #pragma unroll
        for (int ks = 0; ks < 2; ks++) {
            short8 b0 = *(const short8*)&Bl[wc + lr][ks * 32 + lk];
            short8 b1 = *(const short8*)&Bl[wc + 16 + lr][ks * 32 + lk];
            acc[0][0] = mfma16(a[0][ks], b0, acc[0][0]);
            acc[0][1] = mfma16(a[0][ks], b1, acc[0][1]);
            acc[1][0] = mfma16(a[1][ks], b0, acc[1][0]);
            acc[1][1] = mfma16(a[1][ks], b1, acc[1][1]);
        }
        #pragma unroll
        for (int ri = 0; ri < 2; ri++)
            #pragma unroll
            for (int ci = 0; ci < 2; ci++) {
                int lrow = wr + 16 * ri + (lane >> 4) * 4;
                int col  = nq * 64 + wc + 16 * ci + lr;
                #pragma unroll
                for (int r = 0; r < 4; r++) {
                    float ov = cvt_f(otb2[(size_t)(m0 + lrow + r) * HC + col]);
                    go[lrow + r][col] = cvt_bf(sigm(acc[ri][ci][r]) * ov);
                }
            }
    }
    // ---- out GEMM: [64 rows][K=256] @ powb^T -> 64 cols, + residual ----
    f32x4 acc[2][2] = {};
    for (int k0 = 0; k0 < HC; k0 += 32) {
        __syncthreads();
        *(short8*)&Bl[t >> 2][(t & 3) * 8] = *(const short8*)&Bo[(size_t)(t >> 2) * HC + k0 + (t & 3) * 8];
        __syncthreads();
        short8 a0 = *(const short8*)&go[wr + lr][k0 + lk];
        short8 a1 = *(const short8*)&go[wr + 16 + lr][k0 + lk];
        short8 b0 = *(const short8*)&Bl[wc + lr][lk];
        short8 b1 = *(const short8*)&Bl[wc + 16 + lr][lk];
        acc[0][0] = mfma16(a0, b0, acc[0][0]);
        acc[0][1] = mfma16(a0, b1, acc[0][1]);
        acc[1][0] = mfma16(a1, b0, acc[1][0]);
        acc[1][1] = mfma16(a1, b1, acc[1][1]);
    }
    __syncthreads();                            // protect go reuse below
    #pragma unroll
    for (int ri = 0; ri < 2; ri++)
        #pragma unroll
        for (int ci = 0; ci < 2; ci++) {
            int lrow0 = wr + 16 * ri + (lane >> 4) * 4;
            int col   = wc + 16 * ci + lr;
            #pragma unroll
            for (int r = 0; r < 4; r++) {
                size_t idx = (size_t)(m0 + lrow0 + r) * DM + col;
                float v = m[idx] + acc[ri][ci][r];
                mout[idx] = v;
                go[lrow0 + r][col] = cvt_bf(v);  // stash for LN
            }
        }
    __syncthreads();
    // ---- transition LN on the 64x64 tile (wave w: rows w*16..w*16+15) ----
    for (int rr = 0; rr < 16; rr++) {
        int row = wave * 16 + rr;
        float x = cvt_f(go[row][lane]);
        float mu = wred_sum(x) * (1.0f / 64.0f);
        float d = x - mu;
        float var = wred_sum(d * d) * (1.0f / 64.0f);
        tn_bf[(size_t)(m0 + row) * DM + lane] = cvt_bf(d * rsqrtf(var + 1e-5f) * tw + tb);
    }
}

// ---------------- K6: fused SwiGLU transition + residual + OPM-LN -> mout, onb_bf ----------------
__global__ __launch_bounds__(256) void k_fctrans(const ushort_t* __restrict__ A,   // tn_bf [NROWS][64]
                                                 const ushort_t* __restrict__ B1,  // f1b [256][64]
                                                 const ushort_t* __restrict__ B2,  // f2b [256][64]
                                                 const ushort_t* __restrict__ B3,  // f3b [64][256]
                                                 float* __restrict__ mio,
                                                 const float* __restrict__ onw,
                                                 const float* __restrict__ onb,
                                                 ushort_t* __restrict__ onb_bf) {
    int m0 = blockIdx.x * 64;
    __shared__ ushort_t Al[64][72];
    __shared__ ushort_t B1l[64][72];
    __shared__ ushort_t B2l[64][72];
    __shared__ ushort_t hhl[64][264];
    int t = threadIdx.x;
    int srow = t >> 2, sko = (t & 3) * 16;
    int wave = t >> 6, lane = t & 63;
    int wr = (wave >> 1) * 32, wc = (wave & 1) * 32;
    int lk = (lane >> 4) * 8, lr = lane & 15;
    float ow = onw[lane], ob = onb[lane];
    {
        const ushort_t* arow = &A[(size_t)(m0 + srow) * DM + sko];
        *(short8*)&Al[srow][sko]     = *(const short8*)&arow[0];
        *(short8*)&Al[srow][sko + 8] = *(const short8*)&arow[8];
    }
    __syncthreads();
    short8 a[2][2];
    a[0][0] = *(const short8*)&Al[wr + lr][lk];
    a[0][1] = *(const short8*)&Al[wr + lr][32 + lk];
    a[1][0] = *(const short8*)&Al[wr + 16 + lr][lk];
    a[1][1] = *(const short8*)&Al[wr + 16 + lr][32 + lk];
    for (int nq = 0; nq < 4; nq++) {
        __syncthreads();
        {
            const ushort_t* b1r = &B1[(size_t)(nq * 64 + srow) * DM + sko];
            const ushort_t* b2r = &B2[(size_t)(nq * 64 + srow) * DM + sko];
            *(short8*)&B1l[srow][sko]     = *(const short8*)&b1r[0];
            *(short8*)&B1l[srow][sko + 8] = *(const short8*)&b1r[8];
            *(short8*)&B2l[srow][sko]     = *(const short8*)&b2r[0];
            *(short8*)&B2l[srow][sko + 8] = *(const short8*)&b2r[8];
        }
        __syncthreads();
        f32x4 acc1[2][2] = {}, acc2[2][2] = {};
        #pragma unroll
        for (int ks = 0; ks < 2; ks++) {
            short8 p0 = *(const short8*)&B1l[wc + lr][ks * 32 + lk];
            short8 p1 = *(const short8*)&B1l[wc + 16 + lr][ks * 32 + lk];
            short8 q0 = *(const short8*)&B2l[wc + lr][ks * 32 + lk];
            short8 q1 = *(const short8*)&B2l[wc + 16 + lr][ks * 32 + lk];
            acc1[0][0] = mfma16(a[0][ks], p0, acc1[0][0]);
            acc1[0][1] = mfma16(a[0][ks], p1, acc1[0][1]);
            acc1[1][0] = mfma16(a[1][ks], p0, acc1[1][0]);
            acc1[1][1] = mfma16(a[1][ks], p1, acc1[1][1]);
            acc2[0][0] = mfma16(a[0][ks], q0, acc2[0][0]);
            acc2[0][1] = mfma16(a[0][ks], q1, acc2[0][1]);
            acc2[1][0] = mfma16(a[1][ks], q0, acc2[1][0]);
            acc2[1][1] = mfma16(a[1][ks], q1, acc2[1][1]);
        }
        #pragma unroll
        for (int ri = 0; ri < 2; ri++)
            #pragma unroll
            for (int ci = 0; ci < 2; ci++) {
                int lrow = wr + 16 * ri + (lane >> 4) * 4;
                int col  = nq * 64 + wc + 16 * ci + lr;
                #pragma unroll
                for (int r = 0; r < 4; r++) {
                    float a1v = acc1[ri][ci][r], a2v = acc2[ri][ci][r];
                    hhl[lrow + r][col] = cvt_bf(a1v * sigm(a1v) * a2v);
                }
            }
    }
    // fc3: [64][256] @ f3b^T -> 64 cols, residual
    f32x4 acc[2][2] = {};
    for (int k0 = 0; k0 < FF; k0 += 32) {
        __syncthreads();
        *(short8*)&B1l[t >> 2][(t & 3) * 8] = *(const short8*)&B3[(size_t)(t >> 2) * FF + k0 + (t & 3) * 8];
        __syncthreads();
        short8 a0 = *(const short8*)&hhl[wr + lr][k0 + lk];
        short8 a1 = *(const short8*)&hhl[wr + 16 + lr][k0 + lk];
        short8 b0 = *(const short8*)&B1l[wc + lr][lk];
        short8 b1 = *(const short8*)&B1l[wc + 16 + lr][lk];
        acc[0][0] = mfma16(a0, b0, acc[0][0]);
        acc[0][1] = mfma16(a0, b1, acc[0][1]);
        acc[1][0] = mfma16(a1, b0, acc[1][0]);
        acc[1][1] = mfma16(a1, b1, acc[1][1]);
    }
    __syncthreads();                            // protect hhl reuse below
    #pragma unroll
    for (int ri = 0; ri < 2; ri++)
        #pragma unroll
        for (int ci = 0; ci < 2; ci++) {
            int lrow0 = wr + 16 * ri + (lane >> 4) * 4;
            int col   = wc + 16 * ci + lr;
            #pragma unroll
            for (int r = 0; r < 4; r++) {
                size_t idx = (size_t)(m0 + lrow0 + r) * DM + col;
                float v = mio[idx] + acc[ri][ci][r];
                mio[idx] = v;
                hhl[lrow0 + r][col] = cvt_bf(v);  // stash for LN
            }
        }
    __syncthreads();
    // ---- OPM LN on the 64x64 tile ----
    for (int rr = 0; rr < 16; rr++) {
        int row = wave * 16 + rr;
        float x = cvt_f(hhl[row][lane]);
        float mu = wred_sum(x) * (1.0f / 64.0f);
        float d = x - mu;
        float var = wred_sum(d * d) * (1.0f / 64.0f);
        onb_bf[(size_t)(m0 + row) * DM + lane] = cvt_bf(d * rsqrtf(var + 1e-5f) * ow + ob);
    }
}

// ---------------- K7: a/b projection GEMM + mask -> abuf/bbuf [s][n*32+c] ----------------
__global__ __launch_bounds__(256) void k_ab_mfma(const ushort_t* __restrict__ A,
                                                 const ushort_t* __restrict__ Bt,
                                                 const float* __restrict__ smask,
                                                 ushort_t* __restrict__ abuf,
                                                 ushort_t* __restrict__ bbuf) {
    int m0 = blockIdx.x * 64;
    __shared__ ushort_t Al[64][40];
    __shared__ ushort_t Bl[64][40];
    int t = threadIdx.x;
    int srow = t >> 2, sko = (t & 3) * 8;
    int wave = t >> 6, lane = t & 63;
    int wr = (wave >> 1) * 32, wc = (wave & 1) * 32;
    int lk = (lane >> 4) * 8, lr = lane & 15;
    f32x4 acc[2][2] = {};
    for (int k0 = 0; k0 < DM; k0 += 32) {
        *(short8*)&Al[srow][sko] = *(const short8*)&A[(size_t)(m0 + srow) * DM + k0 + sko];
        *(short8*)&Bl[srow][sko] = *(const short8*)&Bt[(size_t)srow * DM + k0 + sko];
        __syncthreads();
        short8 a0 = *(const short8*)&Al[wr + lr][lk];
        short8 a1 = *(const short8*)&Al[wr + 16 + lr][lk];
        short8 b0 = *(const short8*)&Bl[wc + lr][lk];
        short8 b1 = *(const short8*)&Bl[wc + 16 + lr][lk];
        acc[0][0] = mfma16(a0, b0, acc[0][0]);
        acc[0][1] = mfma16(a0, b1, acc[0][1]);
        acc[1][0] = mfma16(a1, b0, acc[1][0]);
        acc[1][1] = mfma16(a1, b1, acc[1][1]);
        __syncthreads();
    }
    #pragma unroll
    for (int ri = 0; ri < 2; ri++)
        #pragma unroll
        for (int ci = 0; ci < 2; ci++) {
            int row0 = m0 + wr + 16 * ri + (lane >> 4) * 4;
            int col  = wc + 16 * ci + lr;               // 0..63
            #pragma unroll
            for (int r = 0; r < 4; r++) {
                int rr = row0 + r;                      // s*NRES+n
                int s = rr / NRES, n = rr % NRES;
                float v = acc[ri][ci][r] * smask[rr];
                if (col < DOP)
                    abuf[(size_t)s * (NRES * DOP) + n * DOP + col] = cvt_bf(v);
                else
                    bbuf[(size_t)s * (NRES * DOP) + n * DOP + (col - DOP)] = cvt_bf(v);
            }
        }
}

// ---------------- K8: mask pair-count Gram tile ----------------
__global__ __launch_bounds__(256) void k_msum(const float* __restrict__ smask,
                                              float* __restrict__ msum) {
    int i0 = blockIdx.y * 64, j0 = blockIdx.x * 64;
    __shared__ float As[16][64];
    __shared__ float Bs[16][64];
    int t = threadIdx.x;
    int ty = t >> 4, tx = t & 15;
    float acc[4][4] = {};
    for (int k0 = 0; k0 < NSEQ; k0 += 16) {
        int kk = t >> 4, x4 = (t & 15) * 4;
        *(float4*)&As[kk][x4] = *(const float4*)&smask[(size_t)(k0 + kk) * NRES + i0 + x4];
        *(float4*)&Bs[kk][x4] = *(const float4*)&smask[(size_t)(k0 + kk) * NRES + j0 + x4];
        __syncthreads();
        #pragma unroll
        for (int k = 0; k < 16; k++) {
            float4 a4 = *(const float4*)&As[k][ty * 4];
            float4 b4 = *(const float4*)&Bs[k][tx * 4];
            float ar[4] = {a4.x, a4.y, a4.z, a4.w};
            float br[4] = {b4.x, b4.y, b4.z, b4.w};
            #pragma unroll
            for (int i2 = 0; i2 < 4; i2++)
                #pragma unroll
                for (int j2 = 0; j2 < 4; j2++)
                    acc[i2][j2] += ar[i2] * br[j2];
        }
        __syncthreads();
    }
    #pragma unroll
    for (int r = 0; r < 4; r++) {
        float4 o4 = make_float4(fmaxf(acc[r][0], 1.0f), fmaxf(acc[r][1], 1.0f),
                                fmaxf(acc[r][2], 1.0f), fmaxf(acc[r][3], 1.0f));
        *(float4*)&msum[(size_t)(i0 + ty * 4 + r) * NRES + j0 + tx * 4] = o4;
    }
}

// ---------------- K9: fused OPM outer GEMM + projection + residual -> zout ----------------
// Main loop: opm tile 128x128 (bf16, BK=64, 8-slot swizzle).  Pack fp8 into ol[16][1040].
// Projection phase is WAVE-LOCAL; per chunk: read ALL fragments into regs, lgkm-drain,
// issue NEXT chunk's gld16s, then MFMA from regs while the next chunk is in flight.
__global__ __launch_bounds__(256) void k_opm_mfma(const ushort_t* __restrict__ At,
                                                  const ushort_t* __restrict__ Bt,
                                                  const uchar_t* __restrict__ opW8,
                                                  const float* __restrict__ opB,
                                                  const float* __restrict__ msum,
                                                  const float* __restrict__ zin,
                                                  float* __restrict__ zout,
                                                  int ib) {
    int m0 = blockIdx.y * 128;                  // over ichunk*32 (il,c)
    int n0 = blockIdx.x * 128;                  // over 12288 (j,d)
    __shared__ ushort_t ABl[2 * 128 * 64];      // Al | Bl contiguous; ol alias spans both
    __shared__ uchar_t Wl[128 * 128];           // 16KB W chunk
    ushort_t* Al = ABl;
    ushort_t* Bl = ABl + 128 * 64;
    uchar_t* ol = (uchar_t*)ABl;                // 16*1040 = 16640B, safe within 32KB ABl
    int t = threadIdx.x;
    int w = t >> 6, lane = t & 63;
    int wr = (w >> 1) * 64, wc = (w & 1) * 64;
    int lq = lane >> 4, lr = lane & 15;
    int rS = lane >> 3;                         // 0..7: row within 8-row gld group
    int cqs = (((lane & 7) ^ rS) << 3);         // 8-slot swizzled source col (ushorts)
    int cS8 = (((lane & 7) ^ rS) << 4);         // same swizzle in bytes (fp8 W)
    f32x4 acc[4][4] = {};                       // rows<-n (quad), cols<-m (lr), swapped
    for (int k0 = 0; k0 < NSEQ; k0 += 64) {
        #pragma unroll
        for (int g = 0; g < 4; g++) {
            int row = w * 32 + g * 8;           // 4 waves cover 128 rows
            gld16(&At[(size_t)(m0 + row + rS) * NSEQ + k0 + cqs], &Al[row * 64]);
            gld16(&Bt[(size_t)(n0 + row + rS) * NSEQ + k0 + cqs], &Bl[row * 64]);
        }
        __syncthreads();
        #pragma unroll
        for (int kk = 0; kk < 2; kk++) {
            short8 af[4], bf2[4];
            #pragma unroll
            for (int i = 0; i < 4; i++) {
                int ra = wr + 16 * i + lr;
                int rb = wc + 16 * i + lr;
                af[i]  = *(const short8*)&Al[ra * 64 + (((kk * 4 + lq) ^ (ra & 7)) << 3)];
                bf2[i] = *(const short8*)&Bl[rb * 64 + (((kk * 4 + lq) ^ (rb & 7)) << 3)];
            }
            #pragma unroll
            for (int ri = 0; ri < 4; ri++)
                #pragma unroll
                for (int ci = 0; ci < 4; ci++)
                    acc[ri][ci] = mfma16(bf2[ci], af[ri], acc[ri][ci]);   // swapped
        }
        __syncthreads();
    }
    // prefetch W chunk 0 (lands under the pack + barrier); Wl untouched by main loop
    #pragma unroll
    for (int g = 0; g < 4; g++) {
        int row = w * 32 + g * 8;
        gld16(&opW8[(size_t)(row + rS) * 1024 + cS8], &Wl[row * 128]);
    }
    // pack fp8 quads into ol (overwrites Al/Bl region, all reads done): row p = il*4+j, byte (c<<5)+dd
    #pragma unroll
    for (int ri = 0; ri < 4; ri++)
        #pragma unroll
        for (int ci = 0; ci < 4; ci++) {
            int ml = wr + 16 * ri + lr;                   // local (il,c)
            int il = ml >> 5, c = ml & 31;
            int nl = wc + 16 * ci + lq * 4;               // local (j,dd), dd quad-aligned
            int j = nl >> 5, dd = nl & 31;
            int p = il * 4 + j;
            int p01  = __builtin_amdgcn_cvt_pk_fp8_f32(acc[ri][ci][0], acc[ri][ci][1], 0, 0);
            int pall = __builtin_amdgcn_cvt_pk_fp8_f32(acc[ri][ci][2], acc[ri][ci][3], p01, 1);
            *(int*)&ol[p * 1040 + (c << 5) + dd] = pall;
        }
    __syncthreads();                            // ol visible to all waves
    // ---- projection (wave-local): out[p=16][e=128] = ol[16][K=1024] @ opW8^T ----
    f32x4 accp[2] = {};                         // wave w covers e in [w*32, w*32+32)
    for (int kc = 0; kc < 8; kc++) {
        asm volatile("s_waitcnt vmcnt(0)" ::: "memory");   // wave's Wl chunk landed
        __builtin_amdgcn_sched_barrier(0);
        // read ALL fragments of this chunk into registers
        i64 afr[4], bfr[4][2];
        #pragma unroll
        for (int ls = 0; ls < 4; ls++) {
            int l = ls * 2 + (lq >> 1);
            int wo = (lq & 1) * 8;
            afr[ls] = *(const i64*)&ol[lr * 1040 + kc * 128 + ls * 32 + lq * 8];
            #pragma unroll
            for (int et = 0; et < 2; et++) {
                int er = w * 32 + et * 16 + lr;
                bfr[ls][et] = *(const i64*)&Wl[er * 128 + ((l ^ (er & 7)) << 4) + wo];
            }
        }
        if (kc < 7) {
            asm volatile("s_waitcnt lgkmcnt(0)" ::: "memory");  // frags in regs; Wl free
            __builtin_amdgcn_sched_barrier(0);
            #pragma unroll
            for (int g = 0; g < 4; g++) {
                int row = w * 32 + g * 8;
                gld16(&opW8[(size_t)(row + rS) * 1024 + (kc + 1) * 128 + cS8], &Wl[row * 128]);
            }
        }
        #pragma unroll
        for (int ls = 0; ls < 4; ls++)
            #pragma unroll
            for (int et = 0; et < 2; et++)
                accp[et] = mfma16f8(bfr[ls][et], afr[ls], accp[et]);   // quad<-e, lr<-p
    }
    // epilogue: z residual + bias + /msum
    {
        int p = lr;
        int ilg = ib + (m0 >> 5) + (p >> 2);
        int jg  = (n0 >> 5) + (p & 3);
        size_t G = (size_t)ilg * NRES + jg;
        float inv = 1.0f / msum[G];
        #pragma unroll
        for (int et = 0; et < 2; et++) {
            int e0 = w * 32 + et * 16 + lq * 4;
            float4 zv = *(const float4*)&zin[G * DZ + e0];
            float4 bv = *(const float4*)&opB[e0];
            float4 o4;
            o4.x = zv.x + accp[et][0] * inv + bv.x;
            o4.y = zv.y + accp[et][1] * inv + bv.y;
            o4.z = zv.z + accp[et][2] * inv + bv.z;
            o4.w = zv.w + accp[et][3] * inv + bv.w;
            *(float4*)&zout[G * DZ + e0] = o4;
        }
    }
}

// ---------------- launch ----------------
extern "C" void kernel_launch(void* const* d_in, const int* in_sizes, int n_in,
                              void* d_out, int out_size, void* d_ws, size_t ws_size,
                              hipStream_t stream) {
    const float* z     = (const float*)d_in[0];
    const float* m     = (const float*)d_in[1];
    const float* tmask = (const float*)d_in[2];
    const float* smask = (const float*)d_in[3];
    const float* nzw   = (const float*)d_in[4];
    const float* nzb   = (const float*)d_in[5];
    const float* pzw   = (const float*)d_in[6];
    const float* nmw   = (const float*)d_in[7];
    const float* nmb   = (const float*)d_in[8];
    const float* pmw   = (const float*)d_in[9];
    const float* pgw   = (const float*)d_in[10];
    const float* pow_  = (const float*)d_in[11];
    const float* tnw   = (const float*)d_in[12];
    const float* tnb_  = (const float*)d_in[13];
    const float* f1    = (const float*)d_in[14];
    const float* f2    = (const float*)d_in[15];
    const float* f3    = (const float*)d_in[16];
    const float* onw   = (const float*)d_in[17];
    const float* onb   = (const float*)d_in[18];
    const float* paw   = (const float*)d_in[19];
    const float* pbw   = (const float*)d_in[20];
    const float* opW   = (const float*)d_in[21];
    const float* opB   = (const float*)d_in[22];

    float* zout = (float*)d_out;
    float* mout = zout + ZTOT;

    char* W = (char*)d_ws;
    // fixed low region
    ushort_t* wsb  = (ushort_t*)(W + 4718592);          //  .. 7,077,888 (bf16 softmax wts)
    ushort_t* mnb  = (ushort_t*)(W + 7077888);          //  .. 19,660,800 (12.6MB)
    ushort_t* vtt  = (ushort_t*)(W + 69992448);         //  .. 120,324,096 (50.3MB)
    ushort_t* otb2 = (ushort_t*)(W + 120324096);        //  .. 170,655,744 (50.3MB)
    // aliases in low region
    ushort_t* tn_bf  = vtt;                 // vtt dead after k_attn_mfma
    ushort_t* onb_bf = mnb;                 // mnb dead after k_gateout
    ushort_t* abuf = (ushort_t*)(W + 69992448 + 12582912);   // vtt+12.6MB (dead after k_tr)
    ushort_t* bbuf = (ushort_t*)(W + 69992448 + 18874368);   // vtt+18.9MB

    // OPM layout: single-pass if workspace is large enough (ws=384MiB observed),
    // else proven 4-chunk fallback. Projection is fused into k_opm (no opmc intermediate).
    bool big = ws_size >= 348200000ull;
    int ichunk, nchunks;
    uchar_t *opW8;
    ushort_t *abt, *bbt;
    float* msum;
    ushort_t *f1b, *f2b, *f3b, *pmwb, *pgwb, *powb, *abwb, *pzwb;
    if (big) {
        ichunk = NRES; nchunks = 1;
        abt  = (ushort_t*)(W + 321650688);              // 6.29MB  .. 327,942,144
        bbt  = (ushort_t*)(W + 327942144);              // 6.29MB  .. 334,233,600 (= abt + R*C, matches k_tr z-stride)
        msum = (float*)(W + 346816512);                 // 0.59MB  .. 347,406,336
        f1b  = (ushort_t*)(W + 347406336);
        f2b  = (ushort_t*)(W + 347439104);
        f3b  = (ushort_t*)(W + 347471872);
        opW8 = (uchar_t*)(W + 347504640);               // 131,072 B (fp8)
        pmwb = (ushort_t*)(W + 347766784);
        pgwb = (ushort_t*)(W + 347799552);
        powb = (ushort_t*)(W + 347832320);
        abwb = (ushort_t*)(W + 347865088);
        pzwb = (ushort_t*)(W + 347873280);              // .. 347,877,376
    } else {
        ichunk = 96; nchunks = 4;
        abt  = otb2;                                    // otb2 dead after k_gateout
        bbt  = (ushort_t*)(W + 120324096 + 6291456);
        msum = (float*)(W + 170655744);
        f1b  = (ushort_t*)(W + 171245568);
        f2b  = (ushort_t*)(W + 171278336);
        f3b  = (ushort_t*)(W + 171311104);
        opW8 = (uchar_t*)(W + 171343872);               // 131,072 B (fp8)
        pmwb = (ushort_t*)(W + 171606016);
        pgwb = (ushort_t*)(W + 171638784);
        powb = (ushort_t*)(W + 171671552);
        abwb = (ushort_t*)(W + 171704320);
        pzwb = (ushort_t*)(W + 171712512);
    }

    k_prep<<<512, 256, 0, stream>>>(f1, f2, f3, opW, pmw, pgw, pow_, paw, pbw, pzw,
                                    f1b, f2b, f3b, opW8, pmwb, pgwb, powb, abwb, pzwb);

    // PairWeightedAveraging
    k_biassm<<<NRES, 256, 0, stream>>>(z, nzw, nzb, pzwb, tmask, wsb);
    k_ln64<<<NROWS / 4, 256, 0, stream>>>(m, nmw, nmb, mnb);
    k_vproj_mfma<<<dim3(HC / 64, NROWS / 64), 256, 0, stream>>>(mnb, pmwb, vtt);
    k_attn_mfma<<<dim3(SD / 128, NRES / 128, NH), 256, 0, stream>>>(wsb, vtt, otb2);
    k_gateout<<<NROWS / 64, 256, 0, stream>>>(mnb, pgwb, otb2, powb, m, mout, tnw, tnb_, tn_bf);

    // Transition (fused, also emits OPM LN)
    k_fctrans<<<NROWS / 64, 256, 0, stream>>>(tn_bf, f1b, f2b, f3b, mout, onw, onb, onb_bf);

    // OuterProductMean (fused outer GEMM + projection)
    k_ab_mfma<<<NROWS / 64, 256, 0, stream>>>(onb_bf, abwb, smask, abuf, bbuf);
    k_tr<<<dim3((NRES * DOP) / 64, NSEQ / 64, 2), 256, 0, stream>>>(abuf, abt, NSEQ, NRES * DOP);
    k_msum<<<dim3(NRES / 64, NRES / 64), 256, 0, stream>>>(smask, msum);
    for (int cb = 0; cb < nchunks; cb++) {
        int ib = cb * ichunk;
        const ushort_t* Achunk = abt + (size_t)(ib * DOP) * NSEQ;
        k_opm_mfma<<<dim3((NRES * DOP) / 128, (ichunk * DOP) / 128), 256, 0, stream>>>(
            Achunk, bbt, opW8, opB, msum, z, zout, ib);
    }
}